// Round 14
// baseline (60.163 us; speedup 1.0000x reference)
//
#include <hip/hip_runtime.h>
#include <hip/hip_bf16.h>

#define NROW 4096      // 2B
#define HALFB 2048     // B
#define CDIM 1024
#define INV_T 2.0f     // 1/0.5
#define NBLK 32        // NROW / 128
#define NTRI 528       // NBLK*(NBLK+1)/2
#define NT 8           // K-tiles of 128
#define RB 512         // bytes per row in fp4 (1024 * 4bit)
#define SCALE_E8M0 122 // 2^-5: data stored as x*32 in e2m1; scale applied on A and B

typedef __attribute__((ext_vector_type(4))) float f32x4;
typedef __attribute__((ext_vector_type(8))) int i32x8;

// round-to-nearest e2m1 encode of q (|q| clamped to 6)
__device__ __forceinline__ unsigned enc_fp4(float q) {
    const unsigned s = q < 0.f ? 8u : 0u;
    const float a = fabsf(q);
    unsigned m;
    if (a < 1.25f) {
        if (a < 0.25f)      m = 0;   // 0.0
        else if (a < 0.75f) m = 1;   // 0.5
        else                m = 2;   // 1.0
    } else if (a < 2.5f) {
        m = (a < 1.75f) ? 3u : 4u;   // 1.5 : 2
    } else {
        if (a < 3.5f)       m = 5;   // 3
        else if (a < 5.0f)  m = 6;   // 4
        else                m = 7;   // 6
    }
    return s | m;
}

// ---------------- Kernel 1: row L2-normalize + fp4(e2m1) pack (+ zero den/pos/cnt) ----------------
__global__ __launch_bounds__(256) void normalize_kernel(
        const float* __restrict__ z1, const float* __restrict__ z2,
        unsigned short* __restrict__ zb4, float* __restrict__ den,
        float* __restrict__ pos, unsigned int* __restrict__ cnt) {
    const int row = blockIdx.x;
    const int t = threadIdx.x;
    if (row < 16) den[row * 256 + t] = 0.f;               // 16*256 = 4096
    else if (row < 24) pos[(row - 16) * 256 + t] = 0.f;   // 8*256 = 2048
    else if (row == 24 && t == 0) *cnt = 0u;              // completion counter
    const float* src = (row < HALFB) ? (z1 + (size_t)row * CDIM)
                                     : (z2 + (size_t)(row - HALFB) * CDIM);
    float4 v = ((const float4*)src)[t];
    float ss = v.x * v.x + v.y * v.y + v.z * v.z + v.w * v.w;
    #pragma unroll
    for (int off = 1; off < 64; off <<= 1) ss += __shfl_xor(ss, off);
    __shared__ float wsum[4];
    const int lane = t & 63, wv = t >> 6;
    if (lane == 0) wsum[wv] = ss;
    __syncthreads();
    const float tot = wsum[0] + wsum[1] + wsum[2] + wsum[3];
    const float scale = 32.0f / fmaxf(sqrtf(tot), 1e-12f);
    const unsigned c0 = enc_fp4(v.x * scale);
    const unsigned c1 = enc_fp4(v.y * scale);
    const unsigned c2 = enc_fp4(v.z * scale);
    const unsigned c3 = enc_fp4(v.w * scale);
    zb4[(size_t)row * 256 + t] = (unsigned short)(c0 | (c1 << 4) | (c2 << 8) | (c3 << 12));
}

// ---------------- Kernel 2: triangle MX-fp4 GEMM + exp/sums + fused last-block loss ----------------
// R11 body verbatim: 528 blocks, 256 thr (4 waves 2x2, per-wave 64x64), BK=128,
// mfma_scale FMT=fp4 uniform scale 2^-5, 2-phase LDS dbuf, source-side swizzle.
// Fused loss tail (R12 retry) with the two regalloc guards:
//   (1) __launch_bounds__(256, 1): allocator may keep ~170 VGPR (R12's heuristic
//       capped at 80 and spilled acc -> 50us; R8's (256,2) cap did the same).
//   (2) __logf instead of precise logf (tiny inline tail, no fat libm sequence).
// Fence pattern proven correct in R12: threadfence -> atomicAdd(cnt); last block
// re-fences and reduces den/pos -> out[0]. cnt zeroed by normalize each launch.
__global__ __launch_bounds__(256, 1) void gemm_den_kernel(
        const unsigned char* __restrict__ zb4, float* __restrict__ den,
        float* __restrict__ pos, unsigned int* __restrict__ cnt,
        float* __restrict__ out) {
    __shared__ __align__(16) unsigned char As[2][128 * 64];
    __shared__ __align__(16) unsigned char Bs[2][128 * 64];

    // XCD swizzle (528 = 8*66, bijective), then triangle decode
    const int orig = blockIdx.x;
    int swz = (orig & 7) * (NTRI / 8) + (orig >> 3);
    int bi = 0, rem = swz;
    while (rem >= NBLK - bi) { rem -= NBLK - bi; ++bi; }
    const int bj = bi + rem;
    const int i0 = bi * 128, j0 = bj * 128;
    const bool diag = (bi == bj);
    const bool is_pos = (bj == bi + 16);   // holds S[i, i+B] on its tile diagonal

    const int tid = threadIdx.x;
    const int wave = tid >> 6, lane = tid & 63;
    const int wr = wave >> 1, wc = wave & 1;

    f32x4 acc[4][4];
    #pragma unroll
    for (int m = 0; m < 4; m++)
        #pragma unroll
        for (int n = 0; n < 4; n++) acc[m][n] = (f32x4){0.f, 0.f, 0.f, 0.f};

    // staging geometry: one gload_lds = 16 rows x 64B; lane: row=lane>>2, chunk=lane&3
    const int srow = lane >> 2;                            // 0..15
    const int schunk = (lane & 3) ^ ((srow >> 1) & 3);     // pre-swizzled source chunk

    const int l15 = lane & 15, ks = lane >> 4;

    auto stage = [&](int buf, int t) {
        const int kb = t * 64;
        #pragma unroll
        for (int c = 0; c < 2; ++c) {
            const int r0 = wave * 32 + c * 16;             // wave-uniform row base
            const unsigned char* ga =
                zb4 + (size_t)(i0 + r0 + srow) * RB + kb + schunk * 16;
            __builtin_amdgcn_global_load_lds(
                (const __attribute__((address_space(1))) void*)ga,
                (__attribute__((address_space(3))) void*)(As[buf] + r0 * 64),
                16, 0, 0);
            // diag blocks: j0 == i0 -> same panel staged twice (uniform schedule)
            const unsigned char* gb =
                zb4 + (size_t)(j0 + r0 + srow) * RB + kb + schunk * 16;
            __builtin_amdgcn_global_load_lds(
                (const __attribute__((address_space(1))) void*)gb,
                (__attribute__((address_space(3))) void*)(Bs[buf] + r0 * 64),
                16, 0, 0);
        }
    };

    // prologue
    stage(0, 0);
    asm volatile("s_waitcnt vmcnt(0)" ::: "memory");
    __builtin_amdgcn_s_barrier();

    #pragma unroll
    for (int t = 0; t < NT; ++t) {
        const int buf = t & 1;
        if (t + 1 < NT) stage(buf ^ 1, t + 1);   // issue-early: hides under compute

        i32x8 b[4];
        #pragma unroll
        for (int n = 0; n < 4; ++n) {
            const int r = wc * 64 + n * 16 + l15;
            const int slot = ks ^ ((r >> 1) & 3);
            const int4 w = *(const int4*)(Bs[buf] + r * 64 + slot * 16);
            b[n] = (i32x8){w.x, w.y, w.z, w.w, 0, 0, 0, 0};
        }
        __builtin_amdgcn_s_setprio(1);
        #pragma unroll
        for (int m = 0; m < 4; ++m) {
            const int r = wr * 64 + m * 16 + l15;
            const int slot = ks ^ ((r >> 1) & 3);
            const int4 w = *(const int4*)(As[buf] + r * 64 + slot * 16);
            const i32x8 a = (i32x8){w.x, w.y, w.z, w.w, 0, 0, 0, 0};
            #pragma unroll
            for (int n = 0; n < 4; ++n)
                acc[m][n] = __builtin_amdgcn_mfma_scale_f32_16x16x128_f8f6f4(
                    a, b[n], acc[m][n],
                    4 /*cbsz: A=fp4*/, 4 /*blgp: B=fp4*/,
                    0, SCALE_E8M0, 0, SCALE_E8M0);
        }
        __builtin_amdgcn_s_setprio(0);
        if (t + 1 < NT) {
            asm volatile("s_waitcnt vmcnt(0)" ::: "memory");  // next buf staged
            __builtin_amdgcn_s_barrier();
        }
    }

    // ---- positives: tiles bj == bi+16 (bi<16) hold S[i, i+B] on their diagonal
    if (is_pos && wr == wc) {
        #pragma unroll
        for (int m = 0; m < 4; ++m) {
            #pragma unroll
            for (int r = 0; r < 4; ++r) {
                if (l15 == ks * 4 + r)
                    pos[i0 + wr * 64 + m * 16 + l15] = acc[m][m][r];
            }
        }
    }

    // ---- epilogue: e = exp(2*s); row-sums -> den[i-panel]; col-sums -> den[j-panel]
    float cs[4] = {0.f, 0.f, 0.f, 0.f};
    #pragma unroll
    for (int m = 0; m < 4; ++m) {
        #pragma unroll
        for (int r = 0; r < 4; ++r) {
            float rs = 0.f;
            #pragma unroll
            for (int n = 0; n < 4; ++n) {
                const float e = __expf(INV_T * acc[m][n][r]);
                rs += e;
                cs[n] += e;
            }
            rs += __shfl_xor(rs, 1);
            rs += __shfl_xor(rs, 2);
            rs += __shfl_xor(rs, 4);
            rs += __shfl_xor(rs, 8);
            if (l15 == 0) {
                const int grow = i0 + wr * 64 + m * 16 + ks * 4 + r;
                atomicAdd(&den[grow], rs);
            }
        }
    }
    if (!diag) {
        #pragma unroll
        for (int n = 0; n < 4; ++n) {
            float c = cs[n];
            c += __shfl_xor(c, 16);
            c += __shfl_xor(c, 32);
            if (lane < 16) {
                const int gcol = j0 + wc * 64 + n * 16 + lane;
                atomicAdd(&den[gcol], c);
            }
        }
    }

    // ---- fused final loss: last block to finish reduces den/pos -> out[0]
    __threadfence();                      // release: my atomics visible device-wide
    __shared__ unsigned lastflag;
    if (tid == 0) lastflag = (atomicAdd(cnt, 1u) == NTRI - 1) ? 1u : 0u;
    __syncthreads();
    if (lastflag) {
        __threadfence();                  // acquire: observe all blocks' atomics
        const float E2 = 7.3890560989306495f;  // exp(2) diagonal term
        float acc2 = 0.f;
        for (int i = tid; i < NROW; i += 256)
            acc2 += INV_T * pos[i & (HALFB - 1)] - __logf(den[i] - E2);
        #pragma unroll
        for (int off = 1; off < 64; off <<= 1) acc2 += __shfl_xor(acc2, off);
        __shared__ float lsum[4];
        if ((tid & 63) == 0) lsum[tid >> 6] = acc2;
        __syncthreads();
        if (tid == 0) out[0] = -(lsum[0] + lsum[1] + lsum[2] + lsum[3]) * (1.0f / NROW);
    }
}

extern "C" void kernel_launch(void* const* d_in, const int* in_sizes, int n_in,
                              void* d_out, int out_size, void* d_ws, size_t ws_size,
                              hipStream_t stream) {
    const float* z1 = (const float*)d_in[0];
    const float* z2 = (const float*)d_in[1];
    float* out = (float*)d_out;

    unsigned short* zb4 = (unsigned short*)d_ws;                     // 2 MB (fp4)
    float* den = (float*)((char*)d_ws + (size_t)NROW * RB);          // 16 KB
    float* pos = den + NROW;                                         // 8 KB
    unsigned int* cnt = (unsigned int*)(pos + HALFB);                // 4 B

    normalize_kernel<<<NROW, 256, 0, stream>>>(z1, z2, zb4, den, pos, cnt);
    gemm_den_kernel<<<NTRI, 256, 0, stream>>>((const unsigned char*)zb4, den, pos, cnt, out);
}

// Round 15
// 37.319 us; speedup vs baseline: 1.6121x; 1.6121x over previous
//
#include <hip/hip_runtime.h>
#include <hip/hip_bf16.h>

#define NROW 4096      // 2B
#define HALFB 2048     // B
#define CDIM 1024
#define INV_T 2.0f     // 1/0.5
#define NBLK 32        // NROW / 128
#define NTRI 528       // NBLK*(NBLK+1)/2
#define NT 4           // K-tiles of 256 (BK=256: 2 MFMA K-steps per stage)
#define RB 512         // bytes per row in fp4 (1024 * 4bit)
#define SCALE_E8M0 122 // 2^-5: data stored as x*32 in e2m1; scale applied on A and B

typedef __attribute__((ext_vector_type(4))) float f32x4;
typedef __attribute__((ext_vector_type(8))) int i32x8;

// round-to-nearest e2m1 encode of q (|q| clamped to 6)
__device__ __forceinline__ unsigned enc_fp4(float q) {
    const unsigned s = q < 0.f ? 8u : 0u;
    const float a = fabsf(q);
    unsigned m;
    if (a < 1.25f) {
        if (a < 0.25f)      m = 0;   // 0.0
        else if (a < 0.75f) m = 1;   // 0.5
        else                m = 2;   // 1.0
    } else if (a < 2.5f) {
        m = (a < 1.75f) ? 3u : 4u;   // 1.5 : 2
    } else {
        if (a < 3.5f)       m = 5;   // 3
        else if (a < 5.0f)  m = 6;   // 4
        else                m = 7;   // 6
    }
    return s | m;
}

// ---------------- Kernel 1: row L2-normalize + fp4(e2m1) pack (+ zero den) ----------------
__global__ __launch_bounds__(256) void normalize_kernel(
        const float* __restrict__ z1, const float* __restrict__ z2,
        unsigned short* __restrict__ zb4, float* __restrict__ den) {
    const int row = blockIdx.x;
    const int t = threadIdx.x;
    if (row < 16) den[row * 256 + t] = 0.f;   // NROW = 16*256; gemm is stream-ordered after
    const float* src = (row < HALFB) ? (z1 + (size_t)row * CDIM)
                                     : (z2 + (size_t)(row - HALFB) * CDIM);
    float4 v = ((const float4*)src)[t];
    float ss = v.x * v.x + v.y * v.y + v.z * v.z + v.w * v.w;
    #pragma unroll
    for (int off = 1; off < 64; off <<= 1) ss += __shfl_xor(ss, off);
    __shared__ float wsum[4];
    const int lane = t & 63, wv = t >> 6;
    if (lane == 0) wsum[wv] = ss;
    __syncthreads();
    const float tot = wsum[0] + wsum[1] + wsum[2] + wsum[3];
    const float scale = 32.0f / fmaxf(sqrtf(tot), 1e-12f);
    const unsigned c0 = enc_fp4(v.x * scale);
    const unsigned c1 = enc_fp4(v.y * scale);
    const unsigned c2 = enc_fp4(v.z * scale);
    const unsigned c3 = enc_fp4(v.w * scale);
    zb4[(size_t)row * 256 + t] = (unsigned short)(c0 | (c1 << 4) | (c2 << 8) | (c3 << 12));
}

// ---------------- Kernel 2: upper-triangle MX-fp4 GEMM + exp + row/col sums + pos ----------------
// 528 blocks, 256 thr (4 waves 2x2, per-wave 64x64). BK=256 as 2 MFMA K-steps per
// staged tile -> NT=4 iterations (R14 lesson: the gemm is latency-CHAIN-bound,
// ~const per iteration; fp8->fp4 throughput halving moved almost nothing. Halving
// the number of stage->drain->barrier rounds attacks the chain directly; per-iter
// compute (~32 MFMA) now fully covers the ~600cy stage latency).
// LDS 64KB: As/Bs [2 buf][128 rows x 128B]; 2 blocks/CU unchanged.
// Swizzle (rule 21): LDS[r][c] holds global 16B chunk c^(r&7) (source pre-swizzle,
// linear gload_lds dest); read of global chunk g at row r uses c = g^(r&7).
// Bank check: 16 l15-lanes, rows 0..15, same g -> 8 distinct chunks x2 = 2-way (free).
// NO fused loss tail (R12/R14: any cross-block tail -> 80-VGPR cap + acc spill).
// Rule #20 / R8: b[4] in regs, a JIT per m, acc compile-time indexed, no VGPR cap.
__global__ __launch_bounds__(256) void gemm_den_kernel(
        const unsigned char* __restrict__ zb4, float* __restrict__ den,
        float* __restrict__ pos) {
    __shared__ __align__(16) unsigned char As[2][128 * 128];
    __shared__ __align__(16) unsigned char Bs[2][128 * 128];

    // XCD swizzle (528 = 8*66, bijective), then triangle decode
    const int orig = blockIdx.x;
    int swz = (orig & 7) * (NTRI / 8) + (orig >> 3);
    int bi = 0, rem = swz;
    while (rem >= NBLK - bi) { rem -= NBLK - bi; ++bi; }
    const int bj = bi + rem;
    const int i0 = bi * 128, j0 = bj * 128;
    const bool diag = (bi == bj);
    const bool is_pos = (bj == bi + 16);   // holds S[i, i+B] on its tile diagonal

    const int tid = threadIdx.x;
    const int wave = tid >> 6, lane = tid & 63;
    const int wr = wave >> 1, wc = wave & 1;

    f32x4 acc[4][4];
    #pragma unroll
    for (int m = 0; m < 4; m++)
        #pragma unroll
        for (int n = 0; n < 4; n++) acc[m][n] = (f32x4){0.f, 0.f, 0.f, 0.f};

    // staging geometry: one gload_lds = 8 rows x 128B (1KB); lane: row=lane>>3, chunk=lane&7
    const int srow = lane >> 3;                  // 0..7
    const int schunk = (lane & 7) ^ srow;        // pre-swizzled source 16B chunk

    const int l15 = lane & 15, ks = lane >> 4;

    auto stage = [&](int buf, int t) {
        const int kb = t * 128;                  // byte offset of this K-tile in a row
        #pragma unroll
        for (int c = 0; c < 4; ++c) {
            const int r0 = wave * 32 + c * 8;    // wave-uniform row base (0..120)
            const unsigned char* ga =
                zb4 + (size_t)(i0 + r0 + srow) * RB + kb + schunk * 16;
            __builtin_amdgcn_global_load_lds(
                (const __attribute__((address_space(1))) void*)ga,
                (__attribute__((address_space(3))) void*)(As[buf] + r0 * 128),
                16, 0, 0);
            // diag blocks: j0 == i0 -> same panel staged twice (uniform schedule)
            const unsigned char* gb =
                zb4 + (size_t)(j0 + r0 + srow) * RB + kb + schunk * 16;
            __builtin_amdgcn_global_load_lds(
                (const __attribute__((address_space(1))) void*)gb,
                (__attribute__((address_space(3))) void*)(Bs[buf] + r0 * 128),
                16, 0, 0);
        }
    };

    // prologue
    stage(0, 0);
    asm volatile("s_waitcnt vmcnt(0)" ::: "memory");
    __builtin_amdgcn_s_barrier();

    #pragma unroll
    for (int t = 0; t < NT; ++t) {
        const int buf = t & 1;
        if (t + 1 < NT) stage(buf ^ 1, t + 1);   // issue-early: hides under 2 K-steps

        #pragma unroll
        for (int kh = 0; kh < 2; ++kh) {
            i32x8 b[4];
            #pragma unroll
            for (int n = 0; n < 4; ++n) {
                const int r = wc * 64 + n * 16 + l15;
                const int c = (kh * 4 + ks) ^ (r & 7);
                const int4 w = *(const int4*)(Bs[buf] + r * 128 + c * 16);
                b[n] = (i32x8){w.x, w.y, w.z, w.w, 0, 0, 0, 0};
            }
            __builtin_amdgcn_s_setprio(1);
            #pragma unroll
            for (int m = 0; m < 4; ++m) {
                const int r = wr * 64 + m * 16 + l15;
                const int c = (kh * 4 + ks) ^ (r & 7);
                const int4 w = *(const int4*)(As[buf] + r * 128 + c * 16);
                const i32x8 a = (i32x8){w.x, w.y, w.z, w.w, 0, 0, 0, 0};
                #pragma unroll
                for (int n = 0; n < 4; ++n)
                    acc[m][n] = __builtin_amdgcn_mfma_scale_f32_16x16x128_f8f6f4(
                        a, b[n], acc[m][n],
                        4 /*cbsz: A=fp4*/, 4 /*blgp: B=fp4*/,
                        0, SCALE_E8M0, 0, SCALE_E8M0);
            }
            __builtin_amdgcn_s_setprio(0);
        }
        if (t + 1 < NT) {
            asm volatile("s_waitcnt vmcnt(0)" ::: "memory");  // next buf staged
            __builtin_amdgcn_s_barrier();
        }
    }

    // ---- positives: tiles bj == bi+16 (bi<16) hold S[i, i+B] on their diagonal
    if (is_pos && wr == wc) {
        #pragma unroll
        for (int m = 0; m < 4; ++m) {
            #pragma unroll
            for (int r = 0; r < 4; ++r) {
                if (l15 == ks * 4 + r)
                    pos[i0 + wr * 64 + m * 16 + l15] = acc[m][m][r];
            }
        }
    }

    // ---- epilogue: e = exp(2*s); row-sums -> den[i-panel]; col-sums -> den[j-panel]
    float cs[4] = {0.f, 0.f, 0.f, 0.f};
    #pragma unroll
    for (int m = 0; m < 4; ++m) {
        #pragma unroll
        for (int r = 0; r < 4; ++r) {
            float rs = 0.f;
            #pragma unroll
            for (int n = 0; n < 4; ++n) {
                const float e = __expf(INV_T * acc[m][n][r]);
                rs += e;
                cs[n] += e;
            }
            rs += __shfl_xor(rs, 1);
            rs += __shfl_xor(rs, 2);
            rs += __shfl_xor(rs, 4);
            rs += __shfl_xor(rs, 8);
            if (l15 == 0) {
                const int grow = i0 + wr * 64 + m * 16 + ks * 4 + r;
                atomicAdd(&den[grow], rs);
            }
        }
    }
    if (!diag) {
        #pragma unroll
        for (int n = 0; n < 4; ++n) {
            float c = cs[n];
            c += __shfl_xor(c, 16);
            c += __shfl_xor(c, 32);
            if (lane < 16) {
                const int gcol = j0 + wc * 64 + n * 16 + lane;
                atomicAdd(&den[gcol], c);
            }
        }
    }
}

// ---------------- Kernel 3: final loss ----------------
__global__ __launch_bounds__(256) void loss_kernel(
        const float* __restrict__ den, const float* __restrict__ pos,
        float* __restrict__ out) {
    const float E2 = 7.3890560989306495f;  // exp(2) = diagonal term
    const int tid = threadIdx.x;
    float acc = 0.f;
    for (int i = tid; i < NROW; i += 256)
        acc += INV_T * pos[i & (HALFB - 1)] - logf(den[i] - E2);
    #pragma unroll
    for (int off = 1; off < 64; off <<= 1) acc += __shfl_xor(acc, off);
    __shared__ float wsum[4];
    const int lane = tid & 63, wv = tid >> 6;
    if (lane == 0) wsum[wv] = acc;
    __syncthreads();
    if (tid == 0) out[0] = -(wsum[0] + wsum[1] + wsum[2] + wsum[3]) * (1.0f / NROW);
}

extern "C" void kernel_launch(void* const* d_in, const int* in_sizes, int n_in,
                              void* d_out, int out_size, void* d_ws, size_t ws_size,
                              hipStream_t stream) {
    const float* z1 = (const float*)d_in[0];
    const float* z2 = (const float*)d_in[1];
    float* out = (float*)d_out;

    unsigned short* zb4 = (unsigned short*)d_ws;                     // 2 MB (fp4)
    float* den = (float*)((char*)d_ws + (size_t)NROW * RB);          // 16 KB
    float* pos = den + NROW;                                         // 8 KB

    normalize_kernel<<<NROW, 256, 0, stream>>>(z1, z2, zb4, den);
    gemm_den_kernel<<<NTRI, 256, 0, stream>>>((const unsigned char*)zb4, den, pos);
    loss_kernel<<<1, 256, 0, stream>>>(den, pos, out);
}

// Round 16
// 29.495 us; speedup vs baseline: 2.0398x; 1.2653x over previous
//
#include <hip/hip_runtime.h>
#include <hip/hip_bf16.h>

#define NROW 4096      // 2B
#define HALFB 2048     // B
#define CDIM 1024
#define INV_T 2.0f     // 1/0.5
#define NBLK 32        // NROW / 128
#define NTRI 528       // NBLK*(NBLK+1)/2
#define NT 8           // K-tiles of 128
#define RB 512         // bytes per row in fp4 (1024 * 4bit)
#define SCALE_E8M0 122 // 2^-5: data stored as x*32 in e2m1; scale applied on A and B

typedef __attribute__((ext_vector_type(4))) float f32x4;
typedef __attribute__((ext_vector_type(8))) int i32x8;

// round-to-nearest e2m1 encode of q (|q| clamped to 6)
__device__ __forceinline__ unsigned enc_fp4(float q) {
    const unsigned s = q < 0.f ? 8u : 0u;
    const float a = fabsf(q);
    unsigned m;
    if (a < 1.25f) {
        if (a < 0.25f)      m = 0;   // 0.0
        else if (a < 0.75f) m = 1;   // 0.5
        else                m = 2;   // 1.0
    } else if (a < 2.5f) {
        m = (a < 1.75f) ? 3u : 4u;   // 1.5 : 2
    } else {
        if (a < 3.5f)       m = 5;   // 3
        else if (a < 5.0f)  m = 6;   // 4
        else                m = 7;   // 6
    }
    return s | m;
}

// ---------------- Kernel 1: row L2-normalize + fp4(e2m1) pack (+ zero den/out) ----------------
__global__ __launch_bounds__(256) void normalize_kernel(
        const float* __restrict__ z1, const float* __restrict__ z2,
        unsigned short* __restrict__ zb4, float* __restrict__ den,
        float* __restrict__ out) {
    const int row = blockIdx.x;
    const int t = threadIdx.x;
    if (row < 16) den[row * 256 + t] = 0.f;       // NROW = 16*256
    else if (row == 16 && t == 0) out[0] = 0.f;   // loss accumulates atomically
    const float* src = (row < HALFB) ? (z1 + (size_t)row * CDIM)
                                     : (z2 + (size_t)(row - HALFB) * CDIM);
    float4 v = ((const float4*)src)[t];
    float ss = v.x * v.x + v.y * v.y + v.z * v.z + v.w * v.w;
    #pragma unroll
    for (int off = 1; off < 64; off <<= 1) ss += __shfl_xor(ss, off);
    __shared__ float wsum[4];
    const int lane = t & 63, wv = t >> 6;
    if (lane == 0) wsum[wv] = ss;
    __syncthreads();
    const float tot = wsum[0] + wsum[1] + wsum[2] + wsum[3];
    const float scale = 32.0f / fmaxf(sqrtf(tot), 1e-12f);
    const unsigned c0 = enc_fp4(v.x * scale);
    const unsigned c1 = enc_fp4(v.y * scale);
    const unsigned c2 = enc_fp4(v.z * scale);
    const unsigned c3 = enc_fp4(v.w * scale);
    zb4[(size_t)row * 256 + t] = (unsigned short)(c0 | (c1 << 4) | (c2 << 8) | (c3 << 12));
}

// ---------------- Kernel 2: upper-triangle MX-fp4 GEMM + exp + row/col sums + pos ----------------
// EXACT R11 body (proven 33.2us anchor). 528 blocks, 256 thr (4 waves 2x2,
// per-wave 64x64). K: 8 tiles of BK=128 via mfma_scale FMT=fp4, uniform 2^-5.
// 2-phase dbuf; STAGE(t+1) before compute(t); vmcnt(0)+barrier per iter.
// Swizzle: 16B chunk c of row r holds global chunk c^((r>>1)&3) (source-side,
// linear LDS dest; same XOR on ds_read). Residual 2-way bank alias = free.
// Ledger of failed variants (do NOT revisit): dbuf-depth/BK=256/8-wave/4-phase/
// 256^2-counted-vmcnt all neutral-to-worse; ANY fused cross-block tail triggers
// an 80-VGPR regalloc cap + acc spill (R12, R14).
__global__ __launch_bounds__(256) void gemm_den_kernel(
        const unsigned char* __restrict__ zb4, float* __restrict__ den,
        float* __restrict__ pos) {
    __shared__ __align__(16) unsigned char As[2][128 * 64];
    __shared__ __align__(16) unsigned char Bs[2][128 * 64];

    // XCD swizzle (528 = 8*66, bijective), then triangle decode
    const int orig = blockIdx.x;
    int swz = (orig & 7) * (NTRI / 8) + (orig >> 3);
    int bi = 0, rem = swz;
    while (rem >= NBLK - bi) { rem -= NBLK - bi; ++bi; }
    const int bj = bi + rem;
    const int i0 = bi * 128, j0 = bj * 128;
    const bool diag = (bi == bj);
    const bool is_pos = (bj == bi + 16);   // holds S[i, i+B] on its tile diagonal

    const int tid = threadIdx.x;
    const int wave = tid >> 6, lane = tid & 63;
    const int wr = wave >> 1, wc = wave & 1;

    f32x4 acc[4][4];
    #pragma unroll
    for (int m = 0; m < 4; m++)
        #pragma unroll
        for (int n = 0; n < 4; n++) acc[m][n] = (f32x4){0.f, 0.f, 0.f, 0.f};

    // staging geometry: one gload_lds = 16 rows x 64B; lane: row=lane>>2, chunk=lane&3
    const int srow = lane >> 2;                            // 0..15
    const int schunk = (lane & 3) ^ ((srow >> 1) & 3);     // pre-swizzled source chunk

    const int l15 = lane & 15, ks = lane >> 4;

    auto stage = [&](int buf, int t) {
        const int kb = t * 64;
        #pragma unroll
        for (int c = 0; c < 2; ++c) {
            const int r0 = wave * 32 + c * 16;             // wave-uniform row base
            const unsigned char* ga =
                zb4 + (size_t)(i0 + r0 + srow) * RB + kb + schunk * 16;
            __builtin_amdgcn_global_load_lds(
                (const __attribute__((address_space(1))) void*)ga,
                (__attribute__((address_space(3))) void*)(As[buf] + r0 * 64),
                16, 0, 0);
            // diag blocks: j0 == i0 -> same panel staged twice (uniform schedule)
            const unsigned char* gb =
                zb4 + (size_t)(j0 + r0 + srow) * RB + kb + schunk * 16;
            __builtin_amdgcn_global_load_lds(
                (const __attribute__((address_space(1))) void*)gb,
                (__attribute__((address_space(3))) void*)(Bs[buf] + r0 * 64),
                16, 0, 0);
        }
    };

    // prologue
    stage(0, 0);
    asm volatile("s_waitcnt vmcnt(0)" ::: "memory");
    __builtin_amdgcn_s_barrier();

    #pragma unroll
    for (int t = 0; t < NT; ++t) {
        const int buf = t & 1;
        if (t + 1 < NT) stage(buf ^ 1, t + 1);   // issue-early: hides under compute

        i32x8 b[4];
        #pragma unroll
        for (int n = 0; n < 4; ++n) {
            const int r = wc * 64 + n * 16 + l15;
            const int slot = ks ^ ((r >> 1) & 3);
            const int4 w = *(const int4*)(Bs[buf] + r * 64 + slot * 16);
            b[n] = (i32x8){w.x, w.y, w.z, w.w, 0, 0, 0, 0};
        }
        __builtin_amdgcn_s_setprio(1);
        #pragma unroll
        for (int m = 0; m < 4; ++m) {
            const int r = wr * 64 + m * 16 + l15;
            const int slot = ks ^ ((r >> 1) & 3);
            const int4 w = *(const int4*)(As[buf] + r * 64 + slot * 16);
            const i32x8 a = (i32x8){w.x, w.y, w.z, w.w, 0, 0, 0, 0};
            #pragma unroll
            for (int n = 0; n < 4; ++n)
                acc[m][n] = __builtin_amdgcn_mfma_scale_f32_16x16x128_f8f6f4(
                    a, b[n], acc[m][n],
                    4 /*cbsz: A=fp4*/, 4 /*blgp: B=fp4*/,
                    0, SCALE_E8M0, 0, SCALE_E8M0);
        }
        __builtin_amdgcn_s_setprio(0);
        if (t + 1 < NT) {
            asm volatile("s_waitcnt vmcnt(0)" ::: "memory");  // next buf staged
            __builtin_amdgcn_s_barrier();
        }
    }

    // ---- positives: tiles bj == bi+16 (bi<16) hold S[i, i+B] on their diagonal
    if (is_pos && wr == wc) {
        #pragma unroll
        for (int m = 0; m < 4; ++m) {
            #pragma unroll
            for (int r = 0; r < 4; ++r) {
                if (l15 == ks * 4 + r)
                    pos[i0 + wr * 64 + m * 16 + l15] = acc[m][m][r];
            }
        }
    }

    // ---- epilogue: e = exp(2*s); row-sums -> den[i-panel]; col-sums -> den[j-panel]
    float cs[4] = {0.f, 0.f, 0.f, 0.f};
    #pragma unroll
    for (int m = 0; m < 4; ++m) {
        #pragma unroll
        for (int r = 0; r < 4; ++r) {
            float rs = 0.f;
            #pragma unroll
            for (int n = 0; n < 4; ++n) {
                const float e = __expf(INV_T * acc[m][n][r]);
                rs += e;
                cs[n] += e;
            }
            rs += __shfl_xor(rs, 1);
            rs += __shfl_xor(rs, 2);
            rs += __shfl_xor(rs, 4);
            rs += __shfl_xor(rs, 8);
            if (l15 == 0) {
                const int grow = i0 + wr * 64 + m * 16 + ks * 4 + r;
                atomicAdd(&den[grow], rs);
            }
        }
    }
    if (!diag) {
        #pragma unroll
        for (int n = 0; n < 4; ++n) {
            float c = cs[n];
            c += __shfl_xor(c, 16);
            c += __shfl_xor(c, 32);
            if (lane < 16) {
                const int gcol = j0 + wc * 64 + n * 16 + lane;
                atomicAdd(&den[gcol], c);
            }
        }
    }
}

// ---------------- Kernel 3: final loss, 16-block parallel (kills the 1-block latency) ----------------
// Each block reduces 256 rows and atomicAdds its (negated, scaled) partial into
// out[0] (zeroed by normalize each launch). FP atomic reorder ~1e-6 << threshold.
__global__ __launch_bounds__(256) void loss_kernel(
        const float* __restrict__ den, const float* __restrict__ pos,
        float* __restrict__ out) {
    const float E2 = 7.3890560989306495f;  // exp(2) = diagonal term
    const int tid = threadIdx.x;
    const int i = blockIdx.x * 256 + tid;
    float acc = INV_T * pos[i & (HALFB - 1)] - logf(den[i] - E2);
    #pragma unroll
    for (int off = 1; off < 64; off <<= 1) acc += __shfl_xor(acc, off);
    __shared__ float wsum[4];
    const int lane = tid & 63, wv = tid >> 6;
    if (lane == 0) wsum[wv] = acc;
    __syncthreads();
    if (tid == 0)
        atomicAdd(out, -(wsum[0] + wsum[1] + wsum[2] + wsum[3]) * (1.0f / NROW));
}

extern "C" void kernel_launch(void* const* d_in, const int* in_sizes, int n_in,
                              void* d_out, int out_size, void* d_ws, size_t ws_size,
                              hipStream_t stream) {
    const float* z1 = (const float*)d_in[0];
    const float* z2 = (const float*)d_in[1];
    float* out = (float*)d_out;

    unsigned short* zb4 = (unsigned short*)d_ws;                     // 2 MB (fp4)
    float* den = (float*)((char*)d_ws + (size_t)NROW * RB);          // 16 KB
    float* pos = den + NROW;                                         // 8 KB

    normalize_kernel<<<NROW, 256, 0, stream>>>(z1, z2, zb4, den, out);
    gemm_den_kernel<<<NTRI, 256, 0, stream>>>((const unsigned char*)zb4, den, pos);
    loss_kernel<<<NROW / 256, 256, 0, stream>>>(den, pos, out);
}